// Round 11
// baseline (101.099 us; speedup 1.0000x reference)
//
#include <hip/hip_runtime.h>
#include <math.h>

#define LL 8
#define AA 4
#define DD 256
#define KF 129            // output frequencies 0..128
#define KH 128            // complex frequencies 0..127; Nyquist packed into k=0 lanes
#define THR 512           // threads per block (8 waves)
#define CLEN 16           // steps per chunk (one chunk per thread, half sequence per block)
#define NES 36            // strict-lower entries, rows 1..8 (unit diagonal implicit)
#define LPAD 37           // padded slot stride

typedef float v2f __attribute__((ext_vector_type(2)));

#define SIX(l2,l1) ((((l2)*((l2)-1))>>1) + (l1))     // l2 in 1..8, l1 < l2
#define SLOT(s)    ((s)*LPAD + ((s)>>1))             // LDS slot base (v2f units)

// ws layout in floats
#define V_OFF   0                                    // v[2*KF] (258 floats, even -> vpart 8B aligned)
#define VP_OFF  (2 * KF)                             // vpart[128][2][36] v2f = 18432 floats
#define CNT_OFF (VP_OFF + 128 * 2 * NES * 2)         // cnt[0]=DFT counter, cnt[1+k]=pair counters

// T-space rescale: S_d[l] = T_d[l] / C(d,l); output row 8 needs 1/C(16384,8)
__device__ __forceinline__ float invCN8() {
  constexpr double c = (16384.0 * 16383.0 * 16382.0 * 16381.0 *
                        16380.0 * 16379.0 * 16378.0 * 16377.0) / 40320.0;
  return (float)(1.0 / c);
}

// acc += b*a : complex (R2=false) or two independent reals in the v2f lanes (R2=true)
template <bool R2>
__device__ __forceinline__ v2f opfma(const v2f b, const v2f a, v2f acc) {
  if (R2) {
    return __builtin_elementwise_fma(b, a, acc);
  } else {
    const v2f bb = (v2f){ b.x,  b.x};
    const v2f bw = (v2f){-b.y,  b.y};
    const v2f as = (v2f){ a.y,  a.x};
    acc = __builtin_elementwise_fma(bb, a,  acc);
    acc = __builtin_elementwise_fma(bw, as, acc);
    return acc;
  }
}

// column-split product of unit-lower-triangular ops: C = B*A (B is the later op)
template <unsigned MASK, bool R2>
__device__ __forceinline__ void prodCols(const v2f* __restrict__ A, const v2f* __restrict__ B,
                                         v2f (&o)[NES]) {
#pragma unroll
  for (int l1 = 0; l1 < 8; ++l1) {
    if ((MASK >> l1) & 1) {
#pragma unroll
      for (int l2 = l1 + 1; l2 <= 8; ++l2) {
        v2f acc = A[SIX(l2, l1)] + B[SIX(l2, l1)];
#pragma unroll
        for (int m = l1 + 1; m < l2; ++m) acc = opfma<R2>(B[SIX(l2, m)], A[SIX(m, l1)], acc);
        o[SIX(l2, l1)] = acc;
      }
    }
  }
}

template <unsigned MASK>
__device__ __forceinline__ void writeCols(v2f* __restrict__ D, const v2f (&o)[NES]) {
#pragma unroll
  for (int l1 = 0; l1 < 8; ++l1) {
    if ((MASK >> l1) & 1) {
#pragma unroll
      for (int l2 = l1 + 1; l2 <= 8; ++l2) D[SIX(l2, l1)] = o[SIX(l2, l1)];
    }
  }
}

// full product with register-array A (earlier) and LDS B (later): o = B*A
template <bool R2>
__device__ __forceinline__ void prodFullRA(const v2f (&A)[NES], const v2f* __restrict__ B,
                                           v2f (&o)[NES]) {
#pragma unroll
  for (int l1 = 0; l1 < 8; ++l1) {
#pragma unroll
    for (int l2 = l1 + 1; l2 <= 8; ++l2) {
      v2f acc = A[SIX(l2, l1)] + B[SIX(l2, l1)];
#pragma unroll
      for (int m = l1 + 1; m < l2; ++m) acc = opfma<R2>(B[SIX(l2, m)], A[SIX(m, l1)], acc);
      o[SIX(l2, l1)] = acc;
    }
  }
}

// chunk phase + level-1 + full tree to ONE operator (result in LDS slots L[0..35])
template <bool R2>
__device__ __forceinline__ void bodyMain(const int* __restrict__ seq, v2f* L,
                                         const float4* qtab, int t, int half) {
  v2f G[NES];
#pragma unroll
  for (int e = 0; e < NES; ++e) G[e] = (v2f){0.f, 0.f};   // identity op

  const int4* sp = (const int4*)(seq + half * (THR * CLEN) + t * CLEN);
  for (int sb = 0; sb < CLEN / 4; ++sb) {
    const int4 cs = sp[sb];
    const int csy[4] = {cs.x, cs.y, cs.z, cs.w};
#pragma unroll
    for (int u = 0; u < 4; ++u) {
      const int c = csy[u];
      float4 qv[LL];
#pragma unroll
      for (int l = 0; l < LL; ++l) qv[l] = qtab[(l << 2) | c];
#pragma unroll
      for (int l = LL; l >= 1; --l) {          // descending: row l reads OLD row l-1
        const float4 q4 = qv[l - 1];
        if (R2) {
          const v2f qa = (v2f){q4.x, q4.y};    // two independent real coefficients
          G[SIX(l, l - 1)] += qa;
#pragma unroll
          for (int l1 = 0; l1 < l - 1; ++l1)
            G[SIX(l, l1)] = __builtin_elementwise_fma(qa, G[SIX(l - 1, l1)], G[SIX(l, l1)]);
        } else {
          const v2f qa = (v2f){q4.x, q4.y};    // (qr, qr)
          const v2f qb = (v2f){q4.z, q4.w};    // (-qi, qi)
          { v2f g = G[SIX(l, l - 1)]; g.x += q4.x; g.y += q4.w; G[SIX(l, l - 1)] = g; }
#pragma unroll
          for (int l1 = 0; l1 < l - 1; ++l1) {
            const v2f H  = G[SIX(l - 1, l1)];
            const v2f Hs = (v2f){H.y, H.x};
            v2f g = G[SIX(l, l1)];
            g = __builtin_elementwise_fma(qa, H,  g);
            g = __builtin_elementwise_fma(qb, Hs, g);
            G[SIX(l, l1)] = g;
          }
        }
      }
    }
  }

  // level 1: 512 chunk ops -> 256 slots
  if (t & 1) {
    v2f* D = L + SLOT(t >> 1);
#pragma unroll
    for (int e = 0; e < NES; ++e) D[e] = G[e];
  }
  __syncthreads();
  if (!(t & 1)) {
    v2f o[NES];
    prodFullRA<R2>(G, L + SLOT(t >> 1), o);
    v2f* D = L + SLOT(t >> 1);
#pragma unroll
    for (int e = 0; e < NES; ++e) D[e] = o[e];
  }
  __syncthreads();

  // column-split tree: 256 -> 128 -> ... -> 1
  const int w = t >> 7;
  const int j = t & 127;
  v2f pc[NES];
  for (int n = 128; n >= 1; n >>= 1) {
    const bool act = (j < n);
    if (act) {
      const v2f* Ab = L + SLOT(2 * j);
      const v2f* Bb = L + SLOT(2 * j + 1);
      switch (w) {
        case 0:  prodCols<0x01, R2>(Ab, Bb, pc); break;
        case 1:  prodCols<0x42, R2>(Ab, Bb, pc); break;
        case 2:  prodCols<0x14, R2>(Ab, Bb, pc); break;
        default: prodCols<0xA8, R2>(Ab, Bb, pc); break;
      }
    }
    __syncthreads();
    if (act) {
      v2f* Db = L + SLOT(j);
      switch (w) {
        case 0:  writeCols<0x01>(Db, pc); break;
        case 1:  writeCols<0x42>(Db, pc); break;
        case 2:  writeCols<0x14>(Db, pc); break;
        default: writeCols<0xA8>(Db, pc); break;
      }
    }
    __syncthreads();
  }
}

// ---------------- main kernel: 256 blocks x 512 thr, block = (k, half) -----------------------
__global__ __launch_bounds__(THR, 1) void kmain(const int* __restrict__ seq,
                                                const float* __restrict__ hemb,
                                                const float* __restrict__ slog,
                                                float* __restrict__ v,
                                                float* __restrict__ vpart,
                                                int* __restrict__ cnt,
                                                float* __restrict__ outp) {
  const int blk  = blockIdx.x;     // 0..255
  const int k    = blk >> 1;       // 0..127 (k==0 also carries Nyquist in lane y)
  const int half = blk & 1;        // sequence half (0 = earlier)
  const int t    = threadIdx.x;    // 0..511
  __shared__ __align__(16) float ldsf[19200];  // 76800 B: 256 op slots / combine scratch
  __shared__ __align__(16) float4 qtab[LL * AA];
  __shared__ float2 twd[256];
  __shared__ float dvr[KF], dvi[KF];
  __shared__ int isLast, isPair;

  // twiddle table (positive angle): twd[m] = (cos, sin)(+2*pi*m/256)
  if (t < 256) {
    float sn, cs;
    __sincosf((float)t * 0.0245436926061702596754894014319f, &sn, &cs);
    twd[t] = make_float2(cs, sn);
  }
  __syncthreads();

  // ================= in-block Q phase: row r = l*4+c per 16-lane group =================
  {
    const int r   = t >> 4;          // 0..31
    const int g16 = t & 15;
    float4 hv[4];
#pragma unroll
    for (int u = 0; u < 4; ++u)
      hv[u] = *(const float4*)(hemb + r * DD + u * 64 + g16 * 4);
    float mx = -1e30f;
#pragma unroll
    for (int u = 0; u < 4; ++u)
      mx = fmaxf(mx, fmaxf(fmaxf(hv[u].x, hv[u].y), fmaxf(hv[u].z, hv[u].w)));
    mx = fmaxf(mx, __shfl_xor(mx, 1));
    mx = fmaxf(mx, __shfl_xor(mx, 2));
    mx = fmaxf(mx, __shfl_xor(mx, 4));
    mx = fmaxf(mx, __shfl_xor(mx, 8));

    float sum = 0.f, cr = 0.f, ci = 0.f;
    if (k > 0) {
#pragma unroll
      for (int u = 0; u < 4; ++u) {
        const float ev[4] = {expf(hv[u].x - mx), expf(hv[u].y - mx),
                             expf(hv[u].z - mx), expf(hv[u].w - mx)};
#pragma unroll
        for (int w2 = 0; w2 < 4; ++w2) {
          const int jj = u * 64 + g16 * 4 + w2;
          const int m = (jj * k) & 255;
          const float2 tv = twd[m];
          sum += ev[w2];
          cr = fmaf(ev[w2], tv.x, cr);
          ci = fmaf(-ev[w2], tv.y, ci);          // negative-angle sin
        }
      }
    } else {
      // pair (k=0, k=128): DFT_0 = sum; DFT_128 = alternating sum (parity of w2)
#pragma unroll
      for (int u = 0; u < 4; ++u) {
        const float ev[4] = {expf(hv[u].x - mx), expf(hv[u].y - mx),
                             expf(hv[u].z - mx), expf(hv[u].w - mx)};
        sum += ev[0] + ev[1] + ev[2] + ev[3];
        cr  += (ev[0] - ev[1]) + (ev[2] - ev[3]);
      }
    }
    sum += __shfl_xor(sum, 1); cr += __shfl_xor(cr, 1); ci += __shfl_xor(ci, 1);
    sum += __shfl_xor(sum, 2); cr += __shfl_xor(cr, 2); ci += __shfl_xor(ci, 2);
    sum += __shfl_xor(sum, 4); cr += __shfl_xor(cr, 4); ci += __shfl_xor(ci, 4);
    sum += __shfl_xor(sum, 8); cr += __shfl_xor(cr, 8); ci += __shfl_xor(ci, 8);

    if (g16 == 0) {
      const float sl = slog[r];
      const float sg = 1.0f / (1.0f + expf(-sl));
      const float q  = fmaf(2.0f, sg, -1.0f);    // 2*sigmoid - 1
      if (k > 0) {
        const float qr = cr * q / sum;
        const float qi = ci * q / sum;
        qtab[r] = make_float4(qr, qr, -qi, qi);  // (qr, qr, -qi, qi)
      } else {
        qtab[r] = make_float4(q, cr * q / sum, 0.f, 0.f);   // (q_k0, q_k128, -, -)
      }
    }
  }
  __syncthreads();

  // ================= chunk + tree: one half-operator in LDS L[0..35] =================
  v2f* L = (v2f*)ldsf;
  if (k == 0) bodyMain<true>(seq, L, qtab, t, half);
  else        bodyMain<false>(seq, L, qtab, t, half);

  // ================= publish half op; second arriver combines + stores v[k] =================
  if (t < NES) {
    union { v2f v2; double d; } u;
    u.v2 = L[t];
    __hip_atomic_store((double*)vpart + (size_t)(k * 2 + half) * NES + t, u.d,
                       __ATOMIC_RELEASE, __HIP_MEMORY_SCOPE_AGENT);
  }
  __syncthreads();
  if (t == 0) {
    const int old = __hip_atomic_fetch_add(&cnt[1 + k], 1, __ATOMIC_ACQ_REL, __HIP_MEMORY_SCOPE_AGENT);
    isPair = (old == 1) ? 1 : 0;
  }
  __syncthreads();
  if (isPair) {
    if (t < 2 * NES) {                 // parallel acquire loads: L[0..35]=half0, L[36..71]=half1
      union { v2f v2; double d; } u;
      u.d = __hip_atomic_load((const double*)vpart + (size_t)(k * 2) * NES + t,
                              __ATOMIC_ACQUIRE, __HIP_MEMORY_SCOPE_AGENT);
      L[t] = u.v2;
    }
    __syncthreads();
    if (t < 64) {                      // lane l holds row l; apply half0 then half1 to e0
      v2f sv[LL + 1];
      sv[0] = (k == 0) ? (v2f){1.f, 1.f} : (v2f){1.f, 0.f};
#pragma unroll
      for (int l = 1; l <= LL; ++l) sv[l] = (v2f){0.f, 0.f};
      for (int gg = 0; gg < 2; ++gg) {
        v2f nv = (v2f){0.f, 0.f};
        if (t >= 1 && t <= LL) {
          nv = sv[t];                               // unit diagonal
          const v2f* Bb = L + gg * NES;
          const int rb = (t * (t - 1)) >> 1;        // SIX(t, 0)
#pragma unroll
          for (int l1 = 0; l1 < 8; ++l1) {
            if (l1 < t) {
              if (k == 0) nv = __builtin_elementwise_fma(Bb[rb + l1], sv[l1], nv);
              else        nv = opfma<false>(Bb[rb + l1], sv[l1], nv);
            }
          }
        }
#pragma unroll
        for (int l = 1; l <= LL; ++l) {
          sv[l].x = __shfl(nv.x, l);
          sv[l].y = __shfl(nv.y, l);
        }
      }
      if (t == 0) {
        if (k == 0) {
          __hip_atomic_store(&v[0],          sv[LL].x, __ATOMIC_RELEASE, __HIP_MEMORY_SCOPE_AGENT);
          __hip_atomic_store(&v[1],          0.0f,     __ATOMIC_RELEASE, __HIP_MEMORY_SCOPE_AGENT);
          __hip_atomic_store(&v[2 * KH],     sv[LL].y, __ATOMIC_RELEASE, __HIP_MEMORY_SCOPE_AGENT);
          __hip_atomic_store(&v[2 * KH + 1], 0.0f,     __ATOMIC_RELEASE, __HIP_MEMORY_SCOPE_AGENT);
        } else {
          __hip_atomic_store(&v[2 * k],     sv[LL].x, __ATOMIC_RELEASE, __HIP_MEMORY_SCOPE_AGENT);
          __hip_atomic_store(&v[2 * k + 1], sv[LL].y, __ATOMIC_RELEASE, __HIP_MEMORY_SCOPE_AGENT);
        }
        __hip_atomic_store(&cnt[1 + k], 0, __ATOMIC_RELAXED, __HIP_MEMORY_SCOPE_AGENT);  // self-reset
      }
    }
  }

  // ================= last arriving of 256 blocks performs the inverse real DFT ================
  __syncthreads();
  if (t == 0) {
    const int old = __hip_atomic_fetch_add(&cnt[0], 1, __ATOMIC_ACQ_REL, __HIP_MEMORY_SCOPE_AGENT);
    isLast = (old == 255) ? 1 : 0;
  }
  __syncthreads();
  if (isLast) {
    if (t < KF) {
      dvr[t] = __hip_atomic_load(&v[2 * t],     __ATOMIC_ACQUIRE, __HIP_MEMORY_SCOPE_AGENT);
      dvi[t] = __hip_atomic_load(&v[2 * t + 1], __ATOMIC_ACQUIRE, __HIP_MEMORY_SCOPE_AGENT);
    }
    if (t == 0)
      __hip_atomic_store(&cnt[0], 0, __ATOMIC_RELEASE, __HIP_MEMORY_SCOPE_AGENT);  // self-reset
    __syncthreads();
    if (t < 256) {
      const float sc = (1.0f / 256.0f) * invCN8();   // undo T-space rescale
      float sum = dvr[0] + ((t & 1) ? -dvr[KH] : dvr[KH]);
      for (int k2 = 1; k2 < KH; ++k2) {
        const int m = (t * k2) & 255;
        const float2 wv = twd[m];
        sum = fmaf(2.0f * dvr[k2], wv.x, sum);
        sum = fmaf(-2.0f * dvi[k2], wv.y, sum);
      }
      outp[t] = sum * sc;
    }
  }
}

extern "C" void kernel_launch(void* const* d_in, const int* in_sizes, int n_in,
                              void* d_out, int out_size, void* d_ws, size_t ws_size,
                              hipStream_t stream) {
  (void)in_sizes; (void)n_in; (void)out_size; (void)ws_size;
  const int*   seq  = (const int*)d_in[0];
  const float* hemb = (const float*)d_in[1];
  const float* slog = (const float*)d_in[2];
  float* ws    = (float*)d_ws;
  float* v     = ws + V_OFF;
  float* vpart = ws + VP_OFF;
  int*   cnt   = (int*)(ws + CNT_OFF);
  float* o     = (float*)d_out;

  hipMemsetAsync(cnt, 0, (1 + KH) * sizeof(int), stream);   // stream-ordered, graph-safe
  hipLaunchKernelGGL(kmain, dim3(256), dim3(THR), 0, stream, seq, hemb, slog, v, vpart, cnt, o);
}

// Round 12
// 92.432 us; speedup vs baseline: 1.0938x; 1.0938x over previous
//
#include <hip/hip_runtime.h>
#include <math.h>

#define LL 8
#define AA 4
#define DD 256
#define KF 129            // frequencies 0..128
#define KH 128            // complex frequencies 0..127; block 128 handles k=128 (real)
#define CLEN 64           // steps per chunk (one chunk per thread)
#define NES 36            // strict-lower entries, rows 1..8 (unit diagonal implicit)
#define LPAD 37           // padded slot stride

typedef float v2f __attribute__((ext_vector_type(2)));

#define SIX(l2,l1) ((((l2)*((l2)-1))>>1) + (l1))     // l2 in 1..8, l1 < l2
#define SLOT(s)    ((s)*LPAD + ((s)>>1))             // complex slot base (v2f units)

// ws layout in floats: v[258]
#define V_OFF   0

// last-arrival counter: device .bss (zero at module load; self-reset by the DFT block)
__device__ int gcnt;

// T-space rescale: S_d[l] = T_d[l] / C(d,l); output row 8 needs 1/C(16384,8)
__device__ __forceinline__ float invCN8() {
  constexpr double c = (16384.0 * 16383.0 * 16382.0 * 16381.0 *
                        16380.0 * 16379.0 * 16378.0 * 16377.0) / 40320.0;
  return (float)(1.0 / c);
}

// acc += b (complex mul) a   -- packed
__device__ __forceinline__ v2f cfma(const v2f b, const v2f a, v2f acc) {
  const v2f bb = (v2f){ b.x,  b.x};
  const v2f bw = (v2f){-b.y,  b.y};
  const v2f as = (v2f){ a.y,  a.x};
  acc = __builtin_elementwise_fma(bb, a,  acc);
  acc = __builtin_elementwise_fma(bw, as, acc);
  return acc;
}

// column-split product of unit-lower-triangular ops: C = B*A (B is the later op)
template <unsigned MASK>
__device__ __forceinline__ void prodCols(const v2f* __restrict__ A, const v2f* __restrict__ B,
                                         v2f (&o)[NES]) {
#pragma unroll
  for (int l1 = 0; l1 < 8; ++l1) {
    if ((MASK >> l1) & 1) {
#pragma unroll
      for (int l2 = l1 + 1; l2 <= 8; ++l2) {
        v2f acc = A[SIX(l2, l1)] + B[SIX(l2, l1)];
#pragma unroll
        for (int m = l1 + 1; m < l2; ++m) acc = cfma(B[SIX(l2, m)], A[SIX(m, l1)], acc);
        o[SIX(l2, l1)] = acc;
      }
    }
  }
}

template <unsigned MASK>
__device__ __forceinline__ void writeCols(v2f* __restrict__ D, const v2f (&o)[NES]) {
#pragma unroll
  for (int l1 = 0; l1 < 8; ++l1) {
    if ((MASK >> l1) & 1) {
#pragma unroll
      for (int l2 = l1 + 1; l2 <= 8; ++l2) D[SIX(l2, l1)] = o[SIX(l2, l1)];
    }
  }
}

// full product with register-array A (earlier) and LDS B (later): o = B*A
__device__ __forceinline__ void prodFullRA(const v2f (&A)[NES], const v2f* __restrict__ B,
                                           v2f (&o)[NES]) {
#pragma unroll
  for (int l1 = 0; l1 < 8; ++l1) {
#pragma unroll
    for (int l2 = l1 + 1; l2 <= 8; ++l2) {
      v2f acc = A[SIX(l2, l1)] + B[SIX(l2, l1)];
#pragma unroll
      for (int m = l1 + 1; m < l2; ++m) acc = cfma(B[SIX(l2, m)], A[SIX(m, l1)], acc);
      o[SIX(l2, l1)] = acc;
    }
  }
}

// real full product, strict-lower unit-triangular
__device__ __forceinline__ void prodR(const float* __restrict__ A, const float* __restrict__ B,
                                      float (&o)[NES]) {
#pragma unroll
  for (int l1 = 0; l1 < 8; ++l1) {
#pragma unroll
    for (int l2 = l1 + 1; l2 <= 8; ++l2) {
      float acc = A[SIX(l2, l1)] + B[SIX(l2, l1)];
#pragma unroll
      for (int m = l1 + 1; m < l2; ++m) acc = fmaf(B[SIX(l2, m)], A[SIX(m, l1)], acc);
      o[SIX(l2, l1)] = acc;
    }
  }
}

// ---------------- single main kernel: per-frequency everything -------------------------------
// 129 blocks x 256 thr. Block k<128: in-block Q (softmax+DFT at k), chunk phase (thread=chunk,
// 64 steps, LDS Q-table), level-1 pair combine, column-split tree 128->8, apply to e0.
// Block 128: Nyquist real path. Last-arriving block does the inverse DFT.
__global__ __launch_bounds__(256, 1) void kmain(const int* __restrict__ seq,
                                                const float* __restrict__ hemb,
                                                const float* __restrict__ slog,
                                                float* __restrict__ v,
                                                float* __restrict__ outp) {
  const int blk = blockIdx.x;    // 0..128
  const int t   = threadIdx.x;   // 0..255
  __shared__ __align__(16) float ldsf[9600];   // 38400 B: 128 complex slots / 256 real slots
  __shared__ __align__(16) float4 qtab[LL * AA];
  __shared__ float2 twd[256];
  __shared__ float dvr[KF], dvi[KF];
  __shared__ int isLast;

  // twiddle table (positive angle): twd[m] = (cos, sin)(+2*pi*m/256)
  {
    float sn, cs;
    __sincosf((float)t * 0.0245436926061702596754894014319f, &sn, &cs);
    twd[t] = make_float2(cs, sn);
  }
  __syncthreads();

  // ================= in-block Q phase =================
  // row r = l*4+c handled by 8-lane group; lane g8 covers j = u*32 + g8*4 + w
  {
    const int r  = t >> 3;
    const int g8 = t & 7;
    float4 hv[8];
#pragma unroll
    for (int u = 0; u < 8; ++u)
      hv[u] = *(const float4*)(hemb + r * DD + u * 32 + g8 * 4);
    float mx = -1e30f;
#pragma unroll
    for (int u = 0; u < 8; ++u) {
      mx = fmaxf(mx, fmaxf(fmaxf(hv[u].x, hv[u].y), fmaxf(hv[u].z, hv[u].w)));
    }
    mx = fmaxf(mx, __shfl_xor(mx, 1));
    mx = fmaxf(mx, __shfl_xor(mx, 2));
    mx = fmaxf(mx, __shfl_xor(mx, 4));

    float sum = 0.0f, cr = 0.0f, ci = 0.0f;
    if (blk < KH) {
      const int k = blk;
#pragma unroll
      for (int u = 0; u < 8; ++u) {
        const float ev[4] = {expf(hv[u].x - mx), expf(hv[u].y - mx),
                             expf(hv[u].z - mx), expf(hv[u].w - mx)};
#pragma unroll
        for (int w = 0; w < 4; ++w) {
          const int j = u * 32 + g8 * 4 + w;
          const int m = (j * k) & 255;
          const float2 tv = twd[m];
          sum += ev[w];
          cr = fmaf(ev[w], tv.x, cr);
          ci = fmaf(-ev[w], tv.y, ci);    // negative-angle sin
        }
      }
    } else {
      // Nyquist: w^j = (-1)^j, parity of j is parity of w
#pragma unroll
      for (int u = 0; u < 8; ++u) {
        const float ev[4] = {expf(hv[u].x - mx), expf(hv[u].y - mx),
                             expf(hv[u].z - mx), expf(hv[u].w - mx)};
        sum += ev[0] + ev[1] + ev[2] + ev[3];
        cr  += (ev[0] - ev[1]) + (ev[2] - ev[3]);
      }
    }
    sum += __shfl_xor(sum, 1); cr += __shfl_xor(cr, 1); ci += __shfl_xor(ci, 1);
    sum += __shfl_xor(sum, 2); cr += __shfl_xor(cr, 2); ci += __shfl_xor(ci, 2);
    sum += __shfl_xor(sum, 4); cr += __shfl_xor(cr, 4); ci += __shfl_xor(ci, 4);

    if (g8 == 0) {
      const float sl = slog[r];
      const float sg = 1.0f / (1.0f + expf(-sl));
      const float q  = fmaf(2.0f, sg, -1.0f);      // 2*sigmoid - 1
      const float sc = q / sum;
      const float qr = cr * sc;
      const float qi = ci * sc;
      qtab[r] = make_float4(qr, qr, -qi, qi);      // (qr, qr, -qi, qi); Nyquist uses .x
    }
  }
  __syncthreads();

  if (blk < KH) {
    // ================= complex path, k = blk =================
    const int k = blk;

    // ---- chunk phase: 64 steps, symbols per-lane, Q via LDS table ----
    v2f G[NES];
#pragma unroll
    for (int e = 0; e < NES; ++e) G[e] = (v2f){0.f, 0.f};   // identity op

    const int4* sp = (const int4*)(seq + t * CLEN);
    for (int sb = 0; sb < CLEN / 4; ++sb) {
      const int4 cs = sp[sb];
      const int csy[4] = {cs.x, cs.y, cs.z, cs.w};
#pragma unroll
      for (int u = 0; u < 4; ++u) {
        const int c = csy[u];
        float4 qv[LL];
#pragma unroll
        for (int l = 0; l < LL; ++l) qv[l] = qtab[(l << 2) | c];
#pragma unroll
        for (int l = LL; l >= 1; --l) {          // descending: row l reads OLD row l-1
          const float4 q4 = qv[l - 1];
          const v2f qa = (v2f){q4.x, q4.y};      // (qr, qr)
          const v2f qb = (v2f){q4.z, q4.w};      // (-qi, qi)
          {
            v2f g = G[SIX(l, l - 1)];
            g.x += q4.x; g.y += q4.w;            // += (qr, qi)
            G[SIX(l, l - 1)] = g;
          }
#pragma unroll
          for (int l1 = 0; l1 < l - 1; ++l1) {
            const v2f H  = G[SIX(l - 1, l1)];
            const v2f Hs = (v2f){H.y, H.x};
            v2f g = G[SIX(l, l1)];
            g = __builtin_elementwise_fma(qa, H,  g);
            g = __builtin_elementwise_fma(qb, Hs, g);
            G[SIX(l, l1)] = g;
          }
        }
      }
    }

    // ---- level 1: 256 ops -> 128 slots in LDS ----
    v2f* L = (v2f*)ldsf;
    if (t & 1) {                       // odd chunk (later of the pair) -> LDS
      v2f* D = L + SLOT(t >> 1);
#pragma unroll
      for (int e = 0; e < NES; ++e) D[e] = G[e];
    }
    __syncthreads();
    if (!(t & 1)) {                    // even chunk combines: C = B(odd) * A(even)
      v2f o[NES];
      prodFullRA(G, L + SLOT(t >> 1), o);
      v2f* D = L + SLOT(t >> 1);
#pragma unroll
      for (int e = 0; e < NES; ++e) D[e] = o[e];
    }
    __syncthreads();

    // ---- column-split tree: 128 -> 64 -> 32 -> 16 -> 8 ----
    const int w = t >> 6;
    const int j = t & 63;
    v2f pc[NES];
    for (int n = 64; n >= 8; n >>= 1) {
      const bool act = (j < n);
      if (act) {
        const v2f* Ab = L + SLOT(2 * j);
        const v2f* Bb = L + SLOT(2 * j + 1);
        switch (w) {
          case 0:  prodCols<0x01>(Ab, Bb, pc); break;
          case 1:  prodCols<0x42>(Ab, Bb, pc); break;
          case 2:  prodCols<0x14>(Ab, Bb, pc); break;
          default: prodCols<0xA8>(Ab, Bb, pc); break;
        }
      }
      __syncthreads();
      if (act) {
        v2f* Db = L + SLOT(j);
        switch (w) {
          case 0:  writeCols<0x01>(Db, pc); break;
          case 1:  writeCols<0x42>(Db, pc); break;
          case 2:  writeCols<0x14>(Db, pc); break;
          default: writeCols<0xA8>(Db, pc); break;
        }
      }
      __syncthreads();
    }

    // ---- apply 8 remaining ops to e0 (wave 0; lane l holds row l) ----
    if (t < 64) {
      v2f sv[LL + 1];
      sv[0] = (v2f){1.f, 0.f};
#pragma unroll
      for (int l = 1; l <= LL; ++l) sv[l] = (v2f){0.f, 0.f};
      for (int gg = 0; gg < 8; ++gg) {
        v2f nv = (v2f){0.f, 0.f};
        if (t >= 1 && t <= LL) {
          nv = sv[t];                               // unit diagonal
          const v2f* Bb = L + SLOT(gg);
          const int rb = (t * (t - 1)) >> 1;        // SIX(t, 0)
#pragma unroll
          for (int l1 = 0; l1 < 8; ++l1) {
            if (l1 < t) nv = cfma(Bb[rb + l1], sv[l1], nv);
          }
        }
#pragma unroll
        for (int l = 1; l <= LL; ++l) {
          sv[l].x = __shfl(nv.x, l);
          sv[l].y = __shfl(nv.y, l);
        }
      }
      if (t == 0) {
        __hip_atomic_store(&v[2 * k],     sv[LL].x, __ATOMIC_RELEASE, __HIP_MEMORY_SCOPE_AGENT);
        __hip_atomic_store(&v[2 * k + 1], sv[LL].y, __ATOMIC_RELEASE, __HIP_MEMORY_SCOPE_AGENT);
      }
    }
  } else {
    // ================= Nyquist (k = 128, real) =================
    float* Lr = ldsf;                       // [256 slots][LPAD] floats
    float Q8[LL][AA];
#pragma unroll
    for (int lc = 0; lc < LL * AA; ++lc) Q8[lc >> 2][lc & 3] = qtab[lc].x;

    float Gr[NES];
#pragma unroll
    for (int e = 0; e < NES; ++e) Gr[e] = 0.f;

    const int4* sp = (const int4*)(seq + t * CLEN);
    for (int sb = 0; sb < CLEN / 4; ++sb) {
      const int4 cs = sp[sb];
      const int csy[4] = {cs.x, cs.y, cs.z, cs.w};
#pragma unroll
      for (int u = 0; u < 4; ++u) {
        const int c = csy[u];
        float Qs[LL];
#pragma unroll
        for (int l = 0; l < LL; ++l) {
          const float qa = (c & 1) ? Q8[l][1] : Q8[l][0];
          const float qb = (c & 1) ? Q8[l][3] : Q8[l][2];
          Qs[l] = (c & 2) ? qb : qa;
        }
#pragma unroll
        for (int l = LL; l >= 1; --l) {
          Gr[SIX(l, l - 1)] += Qs[l - 1];
#pragma unroll
          for (int l1 = 0; l1 < l - 1; ++l1)
            Gr[SIX(l, l1)] = fmaf(Qs[l - 1], Gr[SIX(l - 1, l1)], Gr[SIX(l, l1)]);
        }
      }
    }
#pragma unroll
    for (int e = 0; e < NES; ++e) Lr[t * LPAD + e] = Gr[e];
    __syncthreads();

    float po[NES];
    for (int n = 128; n >= 1; n >>= 1) {   // 256 -> 1 in-place pair tree
      const bool act = (t < n);
      if (act) prodR(Lr + (2 * t) * LPAD, Lr + (2 * t + 1) * LPAD, po);
      __syncthreads();
      if (act) { for (int e = 0; e < NES; ++e) Lr[t * LPAD + e] = po[e]; }
      __syncthreads();
    }
    if (t == 0) {
      __hip_atomic_store(&v[2 * KH],     Lr[SIX(LL, 0)], __ATOMIC_RELEASE, __HIP_MEMORY_SCOPE_AGENT);
      __hip_atomic_store(&v[2 * KH + 1], 0.0f,           __ATOMIC_RELEASE, __HIP_MEMORY_SCOPE_AGENT);
    }
  }

  // ---- last arriving of 129 blocks performs the inverse real DFT ----
  __syncthreads();
  if (t == 0) {
    const int old = __hip_atomic_fetch_add(&gcnt, 1, __ATOMIC_ACQ_REL, __HIP_MEMORY_SCOPE_AGENT);
    isLast = (old == KH) ? 1 : 0;
  }
  __syncthreads();
  if (isLast) {
    if (t < KF) {
      dvr[t] = __hip_atomic_load(&v[2 * t],     __ATOMIC_ACQUIRE, __HIP_MEMORY_SCOPE_AGENT);
      dvi[t] = __hip_atomic_load(&v[2 * t + 1], __ATOMIC_ACQUIRE, __HIP_MEMORY_SCOPE_AGENT);
    }
    if (t == 0) {  // self-reset so every dispatch (incl. rocprof replays) starts clean
      __hip_atomic_store(&gcnt, 0, __ATOMIC_RELEASE, __HIP_MEMORY_SCOPE_AGENT);
    }
    __syncthreads();
    const float sc = (1.0f / 256.0f) * invCN8();   // undo T-space rescale
    float sum = dvr[0] + ((t & 1) ? -dvr[KH] : dvr[KH]);
    for (int k2 = 1; k2 < KH; ++k2) {
      const int m = (t * k2) & 255;
      const float2 wv = twd[m];
      sum = fmaf(2.0f * dvr[k2], wv.x, sum);
      sum = fmaf(-2.0f * dvi[k2], wv.y, sum);
    }
    outp[t] = sum * sc;
  }
}

extern "C" void kernel_launch(void* const* d_in, const int* in_sizes, int n_in,
                              void* d_out, int out_size, void* d_ws, size_t ws_size,
                              hipStream_t stream) {
  (void)in_sizes; (void)n_in; (void)out_size; (void)ws_size;
  const int*   seq  = (const int*)d_in[0];
  const float* hemb = (const float*)d_in[1];
  const float* slog = (const float*)d_in[2];
  float* ws   = (float*)d_ws;
  float* v    = ws + V_OFF;
  float* o    = (float*)d_out;

  hipLaunchKernelGGL(kmain, dim3(KF), dim3(256), 0, stream, seq, hemb, slog, v, o);
}